// Round 6
// baseline (303.805 us; speedup 1.0000x reference)
//
#include <hip/hip_runtime.h>
#include <stdint.h>

// Problem: B=4,Q=75,C=5 -> 1500 groups; D=512; P=H*W=36. fp32 in, fp32 out.
// Round-5 post-mortem: "register-held stream" was silently spilled to scratch
// (VGPR_Count=104 < 152 needed; WRITE_SIZE=93.75 MB vs 12 KB real output).
// This version keeps NO per-thread stream: three coalesced global passes
// (L2/L3-warm after the first), fp32-exact ranking, 42.5 KB LDS, no scratch.
#define NGRP 1500
#define DD 512
#define PP 36
#define DP (DD*PP)        // 18432 fp32 per group per tensor
#define SWEEPS 19         // 18 sweeps x 252 + 1 sweep x 72 float4s = 4608
#define SCALE_CLS 7.0f
#define EPS 1e-12f

__device__ __forceinline__ float waveRed(float x){
  #pragma unroll
  for (int off = 32; off; off >>= 1) x += __shfl_xor(x, off, 64);
  return x;
}

// One block per (b,q,c) group, 256 threads.
// Thread t=(r,c): float4 column-chunk c (positions 4c..4c+3) of rows r+28k.
// Global float4 index (r+28k)*9+c == t + 252k -> perfectly coalesced.
__global__ __launch_bounds__(256, 3)
void topk_fuse(const float* __restrict__ gtrain,
               const float* __restrict__ gtest,
               const int* __restrict__ Kp,
               float* __restrict__ out)
{
  __shared__ float s_rt[DD*9];             // per-row partials, test  (18.4 KB)
  __shared__ float s_rr[DD*9];             // per-row partials, train
  __shared__ float s_tm[DD], s_rm[DD];     // row means (4 KB)
  __shared__ float s_q[PP], s_e[PP];       // per-pos sumsq
  __shared__ float s_a[PP], s_b[PP];       // per-pos dot with other mean
  __shared__ float s_st[PP], s_sr[PP];     // ranking scores
  __shared__ float s_nt[PP], s_nr[PP];     // per-pos norms
  __shared__ float s_wt[PP], s_wr[PP];     // fuse weights
  __shared__ float s_red[12];

  const int t    = threadIdx.x;
  const int lane = t & 63;
  const int wave = t >> 6;
  const int g    = blockIdx.x;
  const int K    = Kp[0];
  const int c    = t % 9;
  const int r    = t / 9;
  const bool act = t < 252;

  const float4* gt4 = (const float4*)(gtest  + (size_t)g * DP);
  const float4* gr4 = (const float4*)(gtrain + (size_t)g * DP);

  if (t < PP) { s_q[t] = 0.f; s_e[t] = 0.f; s_a[t] = 0.f; s_b[t] = 0.f; }

  // ---- Pass 1: col-sumsq (regs) + fp32 row partials -> LDS. No barriers. ----
  float4 q4 = {0,0,0,0}, e4 = {0,0,0,0};
  #pragma unroll
  for (int k = 0; k < SWEEPS; ++k) {
    const bool cact = (k < SWEEPS-1) ? act : (t < 72);
    if (cact) {
      int i = t + 252*k;
      float4 T = gt4[i], R = gr4[i];
      q4.x += T.x*T.x; q4.y += T.y*T.y; q4.z += T.z*T.z; q4.w += T.w*T.w;
      e4.x += R.x*R.x; e4.y += R.y*R.y; e4.z += R.z*R.z; e4.w += R.w*R.w;
      s_rt[i] = T.x + T.y + T.z + T.w;     // linear -> conflict-free
      s_rr[i] = R.x + R.y + R.z + R.w;
    }
  }
  __syncthreads();                                              // A

  // ---- Phase 2: all 512 row means (2 rows/thread) + mean-cosine ----
  float pm2 = 0.f, pr2 = 0.f, pmr = 0.f;
  #pragma unroll
  for (int h = 0; h < 2; ++h) {
    int d = t + 256*h;                     // stride-9 reads: 2-way max (free)
    float st = 0.f, sr = 0.f;
    #pragma unroll
    for (int j = 0; j < 9; ++j) { st += s_rt[d*9 + j]; sr += s_rr[d*9 + j]; }
    float tm = st * (1.0f/36.0f), rm = sr * (1.0f/36.0f);
    s_tm[d] = tm; s_rm[d] = rm;
    pm2 += tm*tm; pr2 += rm*rm; pmr += tm*rm;
  }
  pm2 = waveRed(pm2); pr2 = waveRed(pr2); pmr = waveRed(pmr);
  if (lane == 0) { s_red[wave] = pm2; s_red[4+wave] = pr2; s_red[8+wave] = pmr; }
  __syncthreads();                                              // B
  if (t == 0) {
    float m2 = s_red[0]+s_red[1]+s_red[2]+s_red[3];
    float r2 = s_red[4]+s_red[5]+s_red[6]+s_red[7];
    float mr = s_red[8]+s_red[9]+s_red[10]+s_red[11];
    float n1 = fmaxf(sqrtf(m2), EPS), n2 = fmaxf(sqrtf(r2), EPS);
    out[g] = SCALE_CLS * mr / (n1 * n2);
  }

  // ---- Pass 2: re-read (L2/L3-warm), a/b dots vs broadcast means ----
  float4 a4 = {0,0,0,0}, b4 = {0,0,0,0};
  #pragma unroll
  for (int k = 0; k < SWEEPS; ++k) {
    const bool cact = (k < SWEEPS-1) ? act : (t < 72);
    if (cact) {
      int i = t + 252*k;
      int d = r + 28*k;
      float4 T = gt4[i], R = gr4[i];
      float tm = s_tm[d], rm = s_rm[d];    // 9-lane broadcast, free
      a4.x += T.x*rm; a4.y += T.y*rm; a4.z += T.z*rm; a4.w += T.w*rm;
      b4.x += R.x*tm; b4.y += R.y*tm; b4.z += R.z*tm; b4.w += R.w*tm;
    }
  }
  if (act) {
    int p0 = c*4;
    atomicAdd(&s_q[p0+0], q4.x); atomicAdd(&s_q[p0+1], q4.y);
    atomicAdd(&s_q[p0+2], q4.z); atomicAdd(&s_q[p0+3], q4.w);
    atomicAdd(&s_e[p0+0], e4.x); atomicAdd(&s_e[p0+1], e4.y);
    atomicAdd(&s_e[p0+2], e4.z); atomicAdd(&s_e[p0+3], e4.w);
    atomicAdd(&s_a[p0+0], a4.x); atomicAdd(&s_a[p0+1], a4.y);
    atomicAdd(&s_a[p0+2], a4.z); atomicAdd(&s_a[p0+3], a4.w);
    atomicAdd(&s_b[p0+0], b4.x); atomicAdd(&s_b[p0+1], b4.y);
    atomicAdd(&s_b[p0+2], b4.z); atomicAdd(&s_b[p0+3], b4.w);
  }
  __syncthreads();                                              // C

  // ---- Norms + ranking scores (positive per-group factors dropped) ----
  if (wave < 2 && lane < PP) {
    float q  = wave ? s_e[lane] : s_q[lane];
    float dm = wave ? s_b[lane] : s_a[lane];
    float n  = fmaxf(sqrtf(q), EPS);
    if (wave) { s_nr[lane] = n; s_sr[lane] = dm / n; }
    else      { s_nt[lane] = n; s_st[lane] = dm / n; }
  }
  __syncthreads();                                              // D

  // ---- Top-K via ranks (jnp ties: lower index wins) ----
  if (wave < 2 && lane < PP) {
    const float* sc = wave ? s_sr : s_st;
    const float* nn = wave ? s_nr : s_nt;
    float*       w  = wave ? s_wr : s_wt;
    float mine = sc[lane];
    int rank = 0;
    #pragma unroll
    for (int p = 0; p < PP; ++p) {
      float o = sc[p];
      rank += ((o > mine) || (o == mine && p < lane)) ? 1 : 0;
    }
    w[lane] = (rank < K) ? (1.0f / nn[lane]) : 0.f;
  }
  __syncthreads();                                              // E

  // ---- Pass 3: re-read, fuse partials (1/K cancels in l2norm) ----
  float wt0=0,wt1=0,wt2=0,wt3=0, wr0=0,wr1=0,wr2=0,wr3=0;
  if (act) {
    wt0 = s_wt[4*c+0]; wt1 = s_wt[4*c+1]; wt2 = s_wt[4*c+2]; wt3 = s_wt[4*c+3];
    wr0 = s_wr[4*c+0]; wr1 = s_wr[4*c+1]; wr2 = s_wr[4*c+2]; wr3 = s_wr[4*c+3];
  }
  #pragma unroll
  for (int k = 0; k < SWEEPS; ++k) {
    const bool cact = (k < SWEEPS-1) ? act : (t < 72);
    if (cact) {
      int i = t + 252*k;
      float4 T = gt4[i], R = gr4[i];
      s_rt[i] = T.x*wt0 + T.y*wt1 + T.z*wt2 + T.w*wt3;
      s_rr[i] = R.x*wr0 + R.y*wr1 + R.z*wr2 + R.w*wr3;
    }
  }
  __syncthreads();                                              // F
  float U2 = 0.f, V2 = 0.f, UV = 0.f;
  #pragma unroll
  for (int h = 0; h < 2; ++h) {
    int d = t + 256*h;
    float u = 0.f, v = 0.f;
    #pragma unroll
    for (int j = 0; j < 9; ++j) { u += s_rt[d*9 + j]; v += s_rr[d*9 + j]; }
    U2 += u*u; V2 += v*v; UV += u*v;
  }
  U2 = waveRed(U2); V2 = waveRed(V2); UV = waveRed(UV);
  if (lane == 0) { s_red[wave] = U2; s_red[4+wave] = V2; s_red[8+wave] = UV; }
  __syncthreads();                                              // G
  if (t == 0) {
    float u2 = s_red[0]+s_red[1]+s_red[2]+s_red[3];
    float v2 = s_red[4]+s_red[5]+s_red[6]+s_red[7];
    float uv = s_red[8]+s_red[9]+s_red[10]+s_red[11];
    float nu = fmaxf(sqrtf(u2), EPS), nv = fmaxf(sqrtf(v2), EPS);
    out[NGRP + g] = SCALE_CLS * uv / (nu * nv);
  }
}

extern "C" void kernel_launch(void* const* d_in, const int* in_sizes, int n_in,
                              void* d_out, int out_size, void* d_ws, size_t ws_size,
                              hipStream_t stream)
{
  const float* ftrain = (const float*)d_in[0];
  const float* ftest  = (const float*)d_in[1];
  const int*   Kp     = (const int*)d_in[2];
  float*       out    = (float*)d_out;
  topk_fuse<<<NGRP, 256, 0, stream>>>(ftrain, ftest, Kp, out);
}